// Round 8
// baseline (261.853 us; speedup 1.0000x reference)
//
#include <hip/hip_runtime.h>
#include <math.h>

// MoE gate: logits = x[16384,2048] @ W^T[2048,64]; top-8; softmax over top-8.
//
// Round-10: round-9 (103us, PASSED, MfmaUtil 9.8%) at doubled occupancy.
// Round-9 was latency-bound at 1 block/CU (grid 256, Occupancy 14%): 12
// B-frag L2 loads per k-step (~300-500cyc) vs ~320cyc of issue work, and only
// 2 waves/SIMD of TLP. This round: TOK 64->32, the 8 waves become 8 k-slices
// (kq = wave, 256 k = 8 steps each), grid 512 -> 2 blocks/CU = 4 waves/SIMD.
// LDS 72 KB (part 64 + logits 8) <= 80 KB/block keeps 2-block residency;
// launch_bounds(512,4) caps VGPR at 128 (round-9 used 80, same step body).
//
// Proven structure (unchanged): v_mfma_f32_16x16x32_bf16 with 3-way bf16
// error-compensated split x=xh+xm+xl / W likewise; 6 products hh,mh,hm,lh,
// hl,mm -> dropped terms ~2^-25 rel, below f32 reduction-order noise.
//   - prologue splits W into d_ws (768 KB) in B-frag order: frag (ksg,nt,sp)
//     = 1024 B, lane l dwordx4 at +l*16; n = nt*16+(l&15),
//     k = ksg*32+(l>>4)*8+{2p+h} (pair-order identical to A's packing).
//   - main: block = 512 thr = 8 waves; wave kq: 32 tok x 64 exp x 256 k.
//     Per step: 12 coalesced B-frag dwordx4 (L2-resident ws), 4 x-dwordx4
//     global->reg (full-line use, depth-2 prefetch), split -> 3 A-frags,
//     48 MFMAs. Zero LDS in main loop.
//   - epilogue: part[8][2048] k-partial reduce -> logits[64][32]; lanes
//     0..31 of wave 0: per-lane top-8 (strict >, lax.top_k ties) + softmax.
// C/D layout (m89-verified): col(=expert)=lane&15, row(=token)=(lane>>4)*4+reg.

#define H_DIM 2048
#define N_EXP 64
#define TOPK 8
#define TOK 32

typedef __attribute__((ext_vector_type(8))) short bf16x8;
typedef __attribute__((ext_vector_type(4))) float f32x4;

union FragU { uint4 q; unsigned u[4]; bf16x8 s; };

__device__ inline unsigned cvt_pk_bf16(float lo, float hi) {
  unsigned d;
  asm("v_cvt_pk_bf16_f32 %0, %1, %2" : "=v"(d) : "v"(lo), "v"(hi));
  return d;
}

// split 8 f32 (one A/B fragment worth) into 3 packed-bf16 fragments
__device__ inline void split3(const float* e, unsigned* dh, unsigned* dm,
                              unsigned* dl) {
#pragma unroll
  for (int p = 0; p < 4; ++p) {
    const float f0 = e[2 * p], f1 = e[2 * p + 1];
    const unsigned h = cvt_pk_bf16(f0, f1);
    const float r0 = f0 - __uint_as_float(h << 16);
    const float r1 = f1 - __uint_as_float(h & 0xffff0000u);
    const unsigned m = cvt_pk_bf16(r0, r1);
    const float s0 = r0 - __uint_as_float(m << 16);
    const float s1 = r1 - __uint_as_float(m & 0xffff0000u);
    dl[p] = cvt_pk_bf16(s0, s1);
    dh[p] = h;
    dm[p] = m;
  }
}

// ---- prologue: W[64][2048] f32 -> ws bf16x3 in B-fragment order ----
__global__ __launch_bounds__(256) void w_split_kernel(
    const float* __restrict__ w, uint4* __restrict__ ws) {
  const int id = blockIdx.x * 256 + threadIdx.x;  // 16384 threads
  const int l = id & 63;
  const int nt = (id >> 6) & 3;
  const int ksg = id >> 8;  // 0..63
  const int n = nt * 16 + (l & 15);
  const int kb = ksg * 32 + ((l >> 4) << 3);
  const float* wr = w + (size_t)n * H_DIM + kb;
  const float4 a = *(const float4*)(wr);
  const float4 b = *(const float4*)(wr + 4);
  const float e[8] = {a.x, a.y, a.z, a.w, b.x, b.y, b.z, b.w};
  unsigned dh[4], dm[4], dl[4];
  split3(e, dh, dm, dl);
  const int base = (ksg * 12 + nt * 3) * 64 + l;  // frag i=nt*3+sp stride 64
  ws[base] = make_uint4(dh[0], dh[1], dh[2], dh[3]);
  ws[base + 64] = make_uint4(dm[0], dm[1], dm[2], dm[3]);
  ws[base + 128] = make_uint4(dl[0], dl[1], dl[2], dl[3]);
}

// ---- main kernel ----
__global__ __launch_bounds__(512, 4) void moe_gate_kernel(
    const float* __restrict__ x, const uint4* __restrict__ wf_g,
    float* __restrict__ out, int n_tokens) {
  __shared__ float part[8 * 2048];       // 64 KB: per-wave C fragments
  __shared__ float logits[N_EXP * TOK];  // 8 KB

  const int tid = threadIdx.x;
  const int l = tid & 63;
  const int w = tid >> 6;  // = kq (k-slice id)
  const int kq = __builtin_amdgcn_readfirstlane(w);
  const int t0 = blockIdx.x * TOK;

  // x A-frag addresses: tile t in {0,1}: row = t0+t*16+(l&15),
  // col = kq*256 + s*32 + (l>>4)*8 + h*4
  const float* xp0 =
      x + (size_t)(t0 + (l & 15)) * H_DIM + kq * 256 + ((l >> 4) << 3);
  const float* xp1 = xp0 + (size_t)16 * H_DIM;

  f32x4 acc[2][4];
#pragma unroll
  for (int t = 0; t < 2; ++t)
#pragma unroll
    for (int nt = 0; nt < 4; ++nt) acc[t][nt] = (f32x4){0.f, 0.f, 0.f, 0.f};

  // depth-2 x prefetch registers (8 steps total)
  float4 xa[2][2], xb[2][2], xc[2][2];
  xa[0][0] = *(const float4*)(xp0);
  xa[0][1] = *(const float4*)(xp0 + 4);
  xa[1][0] = *(const float4*)(xp1);
  xa[1][1] = *(const float4*)(xp1 + 4);
  xb[0][0] = *(const float4*)(xp0 + 32);
  xb[0][1] = *(const float4*)(xp0 + 36);
  xb[1][0] = *(const float4*)(xp1 + 32);
  xb[1][1] = *(const float4*)(xp1 + 36);

  // wave kq uses ksg = kq*8 + s -> frag base (ksg*12)*64
  const uint4* wbase = wf_g + (size_t)(kq * 8) * 768 + l;

#pragma unroll 1
  for (int s = 0; s < 8; ++s) {
    // B-frags for this step: 12 coalesced dwordx4 (L2-resident ws)
    uint4 wf[12];
    const uint4* wb = wbase + (size_t)s * 768;
#pragma unroll
    for (int i = 0; i < 12; ++i) wf[i] = wb[i * 64];

    // x prefetch s+2
    if (s + 2 < 8) {
      const float* p0 = xp0 + (s + 2) * 32;
      const float* p1 = xp1 + (s + 2) * 32;
      xc[0][0] = *(const float4*)(p0);
      xc[0][1] = *(const float4*)(p0 + 4);
      xc[1][0] = *(const float4*)(p1);
      xc[1][1] = *(const float4*)(p1 + 4);
    }

    // convert current x -> A-frags (VALU work hides B-frag L2 latency)
    bf16x8 ah[2], am[2], al[2];
#pragma unroll
    for (int t = 0; t < 2; ++t) {
      const float4 v0 = xa[t][0], v1 = xa[t][1];
      const float e[8] = {v0.x, v0.y, v0.z, v0.w, v1.x, v1.y, v1.z, v1.w};
      FragU uh, um, ul;
      split3(e, uh.u, um.u, ul.u);
      ah[t] = uh.s;
      am[t] = um.s;
      al[t] = ul.s;
    }

    // 48 MFMAs: 4 n-tiles x 2 m-tiles x 6 products
#pragma unroll
    for (int nt = 0; nt < 4; ++nt) {
      FragU bh, bm, bl;
      bh.q = wf[nt * 3 + 0];
      bm.q = wf[nt * 3 + 1];
      bl.q = wf[nt * 3 + 2];
#pragma unroll
      for (int t = 0; t < 2; ++t) {
        f32x4 c = acc[t][nt];
        c = __builtin_amdgcn_mfma_f32_16x16x32_bf16(ah[t], bh.s, c, 0, 0, 0);
        c = __builtin_amdgcn_mfma_f32_16x16x32_bf16(am[t], bh.s, c, 0, 0, 0);
        c = __builtin_amdgcn_mfma_f32_16x16x32_bf16(ah[t], bm.s, c, 0, 0, 0);
        c = __builtin_amdgcn_mfma_f32_16x16x32_bf16(al[t], bh.s, c, 0, 0, 0);
        c = __builtin_amdgcn_mfma_f32_16x16x32_bf16(ah[t], bl.s, c, 0, 0, 0);
        c = __builtin_amdgcn_mfma_f32_16x16x32_bf16(am[t], bm.s, c, 0, 0, 0);
        acc[t][nt] = c;
      }
    }

    // rotate prefetch buffers (static indices)
#pragma unroll
    for (int t = 0; t < 2; ++t)
#pragma unroll
      for (int h = 0; h < 2; ++h) {
        xa[t][h] = xb[t][h];
        xb[t][h] = xc[t][h];
      }
  }

  // ---- store per-wave C fragments (2048 floats/wave); reduce; top-8 ----
#pragma unroll
  for (int t = 0; t < 2; ++t)
#pragma unroll
    for (int nt = 0; nt < 4; ++nt)
      *(float4*)&part[w * 2048 + (t * 4 + nt) * 256 + l * 4] =
          make_float4(acc[t][nt][0], acc[t][nt][1], acc[t][nt][2],
                      acc[t][nt][3]);
  __syncthreads();

  // logits[e][t32]: invert C/D mapping, sum the 8 k-slices
  for (int z = tid; z < N_EXP * TOK; z += 512) {
    const int e = z >> 5, t32 = z & 31;
    const int tz = t32 >> 4, r16 = t32 & 15;
    const int q = r16 >> 2, rz = r16 & 3;
    const int idx = (tz * 4 + (e >> 4)) * 256 + (q * 16 + (e & 15)) * 4 + rz;
    float v = ((part[0 * 2048 + idx] + part[1 * 2048 + idx]) +
               (part[2 * 2048 + idx] + part[3 * 2048 + idx])) +
              ((part[4 * 2048 + idx] + part[5 * 2048 + idx]) +
               (part[6 * 2048 + idx] + part[7 * 2048 + idx]));
    logits[z] = v;  // z = e*32 + t32
  }
  __syncthreads();

  if (tid >= TOK) return;  // 32 tokens: lanes 0..31 of wave 0

  // ---- per-lane top-8 over 64 logits (lane = token) ----
  float lg[N_EXP];
#pragma unroll
  for (int e = 0; e < N_EXP; ++e) lg[e] = logits[e * TOK + tid];

  float bw[TOPK];
  int bi[TOPK];
#pragma unroll
  for (int k = 0; k < TOPK; ++k) {
    float m = lg[0];
    int mi = 0;
#pragma unroll
    for (int e = 1; e < N_EXP; ++e) {
      if (lg[e] > m) {  // strict > keeps lowest index on tie (lax.top_k)
        m = lg[e];
        mi = e;
      }
    }
    bw[k] = m;
    bi[k] = mi;
#pragma unroll
    for (int e = 0; e < N_EXP; ++e)
      if (e == mi) lg[e] = -INFINITY;
  }

  // softmax over top-8 == full softmax renormalized to top-8 (exact)
  const float mx = bw[0];
  float ew[TOPK];
  float s = 0.f;
#pragma unroll
  for (int k = 0; k < TOPK; ++k) {
    ew[k] = expf(bw[k] - mx);
    s += ew[k];
  }
  const float inv = 1.f / s;

  float4 w0, w1, i0, i1;
  w0.x = ew[0] * inv; w0.y = ew[1] * inv; w0.z = ew[2] * inv; w0.w = ew[3] * inv;
  w1.x = ew[4] * inv; w1.y = ew[5] * inv; w1.z = ew[6] * inv; w1.w = ew[7] * inv;
  i0.x = (float)bi[0]; i0.y = (float)bi[1]; i0.z = (float)bi[2]; i0.w = (float)bi[3];
  i1.x = (float)bi[4]; i1.y = (float)bi[5]; i1.z = (float)bi[6]; i1.w = (float)bi[7];

  const int t = t0 + tid;
  float4* ow = reinterpret_cast<float4*>(out + (size_t)t * TOPK);
  ow[0] = w0;
  ow[1] = w1;
  float4* oi =
      reinterpret_cast<float4*>(out + (size_t)n_tokens * TOPK + (size_t)t * TOPK);
  oi[0] = i0;
  oi[1] = i1;
}

extern "C" void kernel_launch(void* const* d_in, const int* in_sizes, int n_in,
                              void* d_out, int out_size, void* d_ws,
                              size_t ws_size, hipStream_t stream) {
  const float* x = (const float*)d_in[0];
  const float* w = (const float*)d_in[1];
  float* out = (float*)d_out;
  const int n_tokens = in_sizes[0] / H_DIM;  // 16384
  // prologue: split W into B-fragment-ordered bf16x3 (768 KB in d_ws)
  w_split_kernel<<<64, 256, 0, stream>>>(w, (uint4*)d_ws);
  const int n_blocks = n_tokens / TOK;  // 512
  moe_gate_kernel<<<n_blocks, 512, 0, stream>>>(x, (const uint4*)d_ws, out,
                                                n_tokens);
}

// Round 9
// 218.117 us; speedup vs baseline: 1.2005x; 1.2005x over previous
//
#include <hip/hip_runtime.h>
#include <math.h>

// MoE gate: logits = x[16384,2048] @ W^T[2048,64]; top-8; softmax over top-8.
//
// Round-11: round-10 with the spill fixed (one-line change).
// Round-10 (123us) doubled occupancy as planned (37.6%) but launch_bounds
// (512,4) empirically caps VGPR at 64 on this toolchain (round-7: 64,
// round-10: 64; (512,2) caps at 128, round-6: 128 exactly). The MFMA body
// needs ~80 (round-9 measured) -> 98.7 MB scratch spill ate the win.
// Fix: __launch_bounds__(512, 2) -> 128-VGPR cap (proven no-spill for this
// body); the 72 KB LDS already limits residency to 2 blocks/CU = 4
// waves/SIMD, which is the occupancy round-10 achieved.
//
// Proven structure (unchanged): v_mfma_f32_16x16x32_bf16 with 3-way bf16
// error-compensated split x=xh+xm+xl / W likewise; 6 products hh,mh,hm,lh,
// hl,mm -> dropped terms ~2^-25 rel, below f32 reduction-order noise.
//   - prologue splits W into d_ws (768 KB) in B-frag order: frag (ksg,nt,sp)
//     = 1024 B, lane l dwordx4 at +l*16; n = nt*16+(l&15),
//     k = ksg*32+(l>>4)*8+{2p+h} (pair-order identical to A's packing).
//   - main: grid 512, block = 512 thr = 8 waves; wave kq owns k-slice
//     [kq*256,+256): 32 tok x 64 exp, 8 k-steps. Per step: 12 coalesced
//     B-frag dwordx4 (L2-resident ws), 4 x-dwordx4 global->reg (full-line
//     use, depth-2 prefetch), split -> 3 A-frags, 48 MFMAs. No main-loop LDS.
//   - epilogue: part[8][2048] k-partial reduce -> logits[64][32]; lanes
//     0..31 of wave 0: per-lane top-8 (strict >, lax.top_k ties) + softmax.
// C/D layout (m89-verified): col(=expert)=lane&15, row(=token)=(lane>>4)*4+reg.

#define H_DIM 2048
#define N_EXP 64
#define TOPK 8
#define TOK 32

typedef __attribute__((ext_vector_type(8))) short bf16x8;
typedef __attribute__((ext_vector_type(4))) float f32x4;

union FragU { uint4 q; unsigned u[4]; bf16x8 s; };

__device__ inline unsigned cvt_pk_bf16(float lo, float hi) {
  unsigned d;
  asm("v_cvt_pk_bf16_f32 %0, %1, %2" : "=v"(d) : "v"(lo), "v"(hi));
  return d;
}

// split 8 f32 (one A/B fragment worth) into 3 packed-bf16 fragments
__device__ inline void split3(const float* e, unsigned* dh, unsigned* dm,
                              unsigned* dl) {
#pragma unroll
  for (int p = 0; p < 4; ++p) {
    const float f0 = e[2 * p], f1 = e[2 * p + 1];
    const unsigned h = cvt_pk_bf16(f0, f1);
    const float r0 = f0 - __uint_as_float(h << 16);
    const float r1 = f1 - __uint_as_float(h & 0xffff0000u);
    const unsigned m = cvt_pk_bf16(r0, r1);
    const float s0 = r0 - __uint_as_float(m << 16);
    const float s1 = r1 - __uint_as_float(m & 0xffff0000u);
    dl[p] = cvt_pk_bf16(s0, s1);
    dh[p] = h;
    dm[p] = m;
  }
}

// ---- prologue: W[64][2048] f32 -> ws bf16x3 in B-fragment order ----
__global__ __launch_bounds__(256) void w_split_kernel(
    const float* __restrict__ w, uint4* __restrict__ ws) {
  const int id = blockIdx.x * 256 + threadIdx.x;  // 16384 threads
  const int l = id & 63;
  const int nt = (id >> 6) & 3;
  const int ksg = id >> 8;  // 0..63
  const int n = nt * 16 + (l & 15);
  const int kb = ksg * 32 + ((l >> 4) << 3);
  const float* wr = w + (size_t)n * H_DIM + kb;
  const float4 a = *(const float4*)(wr);
  const float4 b = *(const float4*)(wr + 4);
  const float e[8] = {a.x, a.y, a.z, a.w, b.x, b.y, b.z, b.w};
  unsigned dh[4], dm[4], dl[4];
  split3(e, dh, dm, dl);
  const int base = (ksg * 12 + nt * 3) * 64 + l;  // frag i=nt*3+sp stride 64
  ws[base] = make_uint4(dh[0], dh[1], dh[2], dh[3]);
  ws[base + 64] = make_uint4(dm[0], dm[1], dm[2], dm[3]);
  ws[base + 128] = make_uint4(dl[0], dl[1], dl[2], dl[3]);
}

// ---- main kernel ----
__global__ __launch_bounds__(512, 2) void moe_gate_kernel(
    const float* __restrict__ x, const uint4* __restrict__ wf_g,
    float* __restrict__ out, int n_tokens) {
  __shared__ float part[8 * 2048];       // 64 KB: per-wave C fragments
  __shared__ float logits[N_EXP * TOK];  // 8 KB

  const int tid = threadIdx.x;
  const int l = tid & 63;
  const int w = tid >> 6;  // = kq (k-slice id)
  const int kq = __builtin_amdgcn_readfirstlane(w);
  const int t0 = blockIdx.x * TOK;

  // x A-frag addresses: tile t in {0,1}: row = t0+t*16+(l&15),
  // col = kq*256 + s*32 + (l>>4)*8 + h*4
  const float* xp0 =
      x + (size_t)(t0 + (l & 15)) * H_DIM + kq * 256 + ((l >> 4) << 3);
  const float* xp1 = xp0 + (size_t)16 * H_DIM;

  f32x4 acc[2][4];
#pragma unroll
  for (int t = 0; t < 2; ++t)
#pragma unroll
    for (int nt = 0; nt < 4; ++nt) acc[t][nt] = (f32x4){0.f, 0.f, 0.f, 0.f};

  // depth-2 x prefetch registers (8 steps total)
  float4 xa[2][2], xb[2][2], xc[2][2];
  xa[0][0] = *(const float4*)(xp0);
  xa[0][1] = *(const float4*)(xp0 + 4);
  xa[1][0] = *(const float4*)(xp1);
  xa[1][1] = *(const float4*)(xp1 + 4);
  xb[0][0] = *(const float4*)(xp0 + 32);
  xb[0][1] = *(const float4*)(xp0 + 36);
  xb[1][0] = *(const float4*)(xp1 + 32);
  xb[1][1] = *(const float4*)(xp1 + 36);

  // wave kq uses ksg = kq*8 + s -> frag base (ksg*12)*64
  const uint4* wbase = wf_g + (size_t)(kq * 8) * 768 + l;

#pragma unroll 1
  for (int s = 0; s < 8; ++s) {
    // B-frags for this step: 12 coalesced dwordx4 (L2-resident ws)
    uint4 wf[12];
    const uint4* wb = wbase + (size_t)s * 768;
#pragma unroll
    for (int i = 0; i < 12; ++i) wf[i] = wb[i * 64];

    // x prefetch s+2
    if (s + 2 < 8) {
      const float* p0 = xp0 + (s + 2) * 32;
      const float* p1 = xp1 + (s + 2) * 32;
      xc[0][0] = *(const float4*)(p0);
      xc[0][1] = *(const float4*)(p0 + 4);
      xc[1][0] = *(const float4*)(p1);
      xc[1][1] = *(const float4*)(p1 + 4);
    }

    // convert current x -> A-frags (VALU work hides B-frag L2 latency)
    bf16x8 ah[2], am[2], al[2];
#pragma unroll
    for (int t = 0; t < 2; ++t) {
      const float4 v0 = xa[t][0], v1 = xa[t][1];
      const float e[8] = {v0.x, v0.y, v0.z, v0.w, v1.x, v1.y, v1.z, v1.w};
      FragU uh, um, ul;
      split3(e, uh.u, um.u, ul.u);
      ah[t] = uh.s;
      am[t] = um.s;
      al[t] = ul.s;
    }

    // 48 MFMAs: 4 n-tiles x 2 m-tiles x 6 products
#pragma unroll
    for (int nt = 0; nt < 4; ++nt) {
      FragU bh, bm, bl;
      bh.q = wf[nt * 3 + 0];
      bm.q = wf[nt * 3 + 1];
      bl.q = wf[nt * 3 + 2];
#pragma unroll
      for (int t = 0; t < 2; ++t) {
        f32x4 c = acc[t][nt];
        c = __builtin_amdgcn_mfma_f32_16x16x32_bf16(ah[t], bh.s, c, 0, 0, 0);
        c = __builtin_amdgcn_mfma_f32_16x16x32_bf16(am[t], bh.s, c, 0, 0, 0);
        c = __builtin_amdgcn_mfma_f32_16x16x32_bf16(ah[t], bm.s, c, 0, 0, 0);
        c = __builtin_amdgcn_mfma_f32_16x16x32_bf16(al[t], bh.s, c, 0, 0, 0);
        c = __builtin_amdgcn_mfma_f32_16x16x32_bf16(ah[t], bl.s, c, 0, 0, 0);
        c = __builtin_amdgcn_mfma_f32_16x16x32_bf16(am[t], bm.s, c, 0, 0, 0);
        acc[t][nt] = c;
      }
    }

    // rotate prefetch buffers (static indices)
#pragma unroll
    for (int t = 0; t < 2; ++t)
#pragma unroll
      for (int h = 0; h < 2; ++h) {
        xa[t][h] = xb[t][h];
        xb[t][h] = xc[t][h];
      }
  }

  // ---- store per-wave C fragments (2048 floats/wave); reduce; top-8 ----
#pragma unroll
  for (int t = 0; t < 2; ++t)
#pragma unroll
    for (int nt = 0; nt < 4; ++nt)
      *(float4*)&part[w * 2048 + (t * 4 + nt) * 256 + l * 4] =
          make_float4(acc[t][nt][0], acc[t][nt][1], acc[t][nt][2],
                      acc[t][nt][3]);
  __syncthreads();

  // logits[e][t32]: invert C/D mapping, sum the 8 k-slices
  for (int z = tid; z < N_EXP * TOK; z += 512) {
    const int e = z >> 5, t32 = z & 31;
    const int tz = t32 >> 4, r16 = t32 & 15;
    const int q = r16 >> 2, rz = r16 & 3;
    const int idx = (tz * 4 + (e >> 4)) * 256 + (q * 16 + (e & 15)) * 4 + rz;
    float v = ((part[0 * 2048 + idx] + part[1 * 2048 + idx]) +
               (part[2 * 2048 + idx] + part[3 * 2048 + idx])) +
              ((part[4 * 2048 + idx] + part[5 * 2048 + idx]) +
               (part[6 * 2048 + idx] + part[7 * 2048 + idx]));
    logits[z] = v;  // z = e*32 + t32
  }
  __syncthreads();

  if (tid >= TOK) return;  // 32 tokens: lanes 0..31 of wave 0

  // ---- per-lane top-8 over 64 logits (lane = token) ----
  float lg[N_EXP];
#pragma unroll
  for (int e = 0; e < N_EXP; ++e) lg[e] = logits[e * TOK + tid];

  float bw[TOPK];
  int bi[TOPK];
#pragma unroll
  for (int k = 0; k < TOPK; ++k) {
    float m = lg[0];
    int mi = 0;
#pragma unroll
    for (int e = 1; e < N_EXP; ++e) {
      if (lg[e] > m) {  // strict > keeps lowest index on tie (lax.top_k)
        m = lg[e];
        mi = e;
      }
    }
    bw[k] = m;
    bi[k] = mi;
#pragma unroll
    for (int e = 0; e < N_EXP; ++e)
      if (e == mi) lg[e] = -INFINITY;
  }

  // softmax over top-8 == full softmax renormalized to top-8 (exact)
  const float mx = bw[0];
  float ew[TOPK];
  float s = 0.f;
#pragma unroll
  for (int k = 0; k < TOPK; ++k) {
    ew[k] = expf(bw[k] - mx);
    s += ew[k];
  }
  const float inv = 1.f / s;

  float4 w0, w1, i0, i1;
  w0.x = ew[0] * inv; w0.y = ew[1] * inv; w0.z = ew[2] * inv; w0.w = ew[3] * inv;
  w1.x = ew[4] * inv; w1.y = ew[5] * inv; w1.z = ew[6] * inv; w1.w = ew[7] * inv;
  i0.x = (float)bi[0]; i0.y = (float)bi[1]; i0.z = (float)bi[2]; i0.w = (float)bi[3];
  i1.x = (float)bi[4]; i1.y = (float)bi[5]; i1.z = (float)bi[6]; i1.w = (float)bi[7];

  const int t = t0 + tid;
  float4* ow = reinterpret_cast<float4*>(out + (size_t)t * TOPK);
  ow[0] = w0;
  ow[1] = w1;
  float4* oi =
      reinterpret_cast<float4*>(out + (size_t)n_tokens * TOPK + (size_t)t * TOPK);
  oi[0] = i0;
  oi[1] = i1;
}

extern "C" void kernel_launch(void* const* d_in, const int* in_sizes, int n_in,
                              void* d_out, int out_size, void* d_ws,
                              size_t ws_size, hipStream_t stream) {
  const float* x = (const float*)d_in[0];
  const float* w = (const float*)d_in[1];
  float* out = (float*)d_out;
  const int n_tokens = in_sizes[0] / H_DIM;  // 16384
  // prologue: split W into B-fragment-ordered bf16x3 (768 KB in d_ws)
  w_split_kernel<<<64, 256, 0, stream>>>(w, (uint4*)d_ws);
  const int n_blocks = n_tokens / TOK;  // 512
  moe_gate_kernel<<<n_blocks, 512, 0, stream>>>(x, (const uint4*)d_ws, out,
                                                n_tokens);
}

// Round 10
// 211.252 us; speedup vs baseline: 1.2395x; 1.0325x over previous
//
#include <hip/hip_runtime.h>
#include <math.h>

// MoE gate: logits = x[16384,2048] @ W^T[2048,64]; top-8; softmax over top-8.
//
// Round-12: round-9's verified geometry + explicit load-stream decoupling.
// Round-9/11 stall diagnosis: B-frags were consumed in the SAME step they
// were issued, interleaved with HBM x-loads; vmcnt retires in issue order,
// so every B-wait sat behind a ~900-cyc x-load -> each k-step paid a full
// HBM round trip (round-9: 15.5K cyc/step measured vs ~1K of work).
// Fix (main loop only; geometry/epilogue = round-9 verbatim):
//   - wfB register double-buffer: step s issues B for s+1 FIRST (L2-fast,
//     retires early in the in-order vmcnt stream), x for s+2 LAST (HBM-slow,
//     2 steps of lead); MFMA consumes wfA loaded a full step earlier ->
//     compiler emits vmcnt(16), zero load latency on the critical path.
//   - needs ~215 VGPR -> __launch_bounds__(512,1) (empirical cap 256;
//     (512,2)->128, (512,4)->64). 2 waves/SIMD: ILP-for-TLP trade.
//   - rotation via static-index moves under #pragma unroll 2 (copy-prop).
//
// Proven numerics (unchanged): v_mfma_f32_16x16x32_bf16, 3-way bf16 split
// x=xh+xm+xl / W likewise, 6 products hh,mh,hm,lh,hl,mm (~2^-25 rel error).
// Prologue splits W into d_ws (768 KB) in B-frag order (frag (ksg,nt,sp) =
// 1024 B; lane l dwordx4 at +l*16; n = nt*16+(l&15), k = ksg*32+(l>>4)*8+
// {2p+h}, pair-order identical to A packing).
// C/D layout (m89-verified): col(=expert)=lane&15, row(=token)=(lane>>4)*4+reg.

#define H_DIM 2048
#define N_EXP 64
#define TOPK 8
#define TOK 64
#define NSTEP 16

typedef __attribute__((ext_vector_type(8))) short bf16x8;
typedef __attribute__((ext_vector_type(4))) float f32x4;

union FragU { uint4 q; unsigned u[4]; bf16x8 s; };

__device__ inline unsigned cvt_pk_bf16(float lo, float hi) {
  unsigned d;
  asm("v_cvt_pk_bf16_f32 %0, %1, %2" : "=v"(d) : "v"(lo), "v"(hi));
  return d;
}

// split 8 f32 (one A/B fragment worth) into 3 packed-bf16 fragments
__device__ inline void split3(const float* e, unsigned* dh, unsigned* dm,
                              unsigned* dl) {
#pragma unroll
  for (int p = 0; p < 4; ++p) {
    const float f0 = e[2 * p], f1 = e[2 * p + 1];
    const unsigned h = cvt_pk_bf16(f0, f1);
    const float r0 = f0 - __uint_as_float(h << 16);
    const float r1 = f1 - __uint_as_float(h & 0xffff0000u);
    const unsigned m = cvt_pk_bf16(r0, r1);
    const float s0 = r0 - __uint_as_float(m << 16);
    const float s1 = r1 - __uint_as_float(m & 0xffff0000u);
    dl[p] = cvt_pk_bf16(s0, s1);
    dh[p] = h;
    dm[p] = m;
  }
}

// ---- prologue: W[64][2048] f32 -> ws bf16x3 in B-fragment order ----
__global__ __launch_bounds__(256) void w_split_kernel(
    const float* __restrict__ w, uint4* __restrict__ ws) {
  const int id = blockIdx.x * 256 + threadIdx.x;  // 16384 threads
  const int l = id & 63;
  const int nt = (id >> 6) & 3;
  const int ksg = id >> 8;  // 0..63
  const int n = nt * 16 + (l & 15);
  const int kb = ksg * 32 + ((l >> 4) << 3);
  const float* wr = w + (size_t)n * H_DIM + kb;
  const float4 a = *(const float4*)(wr);
  const float4 b = *(const float4*)(wr + 4);
  const float e[8] = {a.x, a.y, a.z, a.w, b.x, b.y, b.z, b.w};
  unsigned dh[4], dm[4], dl[4];
  split3(e, dh, dm, dl);
  const int base = (ksg * 12 + nt * 3) * 64 + l;  // frag i=nt*3+sp stride 64
  ws[base] = make_uint4(dh[0], dh[1], dh[2], dh[3]);
  ws[base + 64] = make_uint4(dm[0], dm[1], dm[2], dm[3]);
  ws[base + 128] = make_uint4(dl[0], dl[1], dl[2], dl[3]);
}

// ---- main-loop helpers (array-reference params keep indices static) ----
__device__ __forceinline__ void load_b(uint4 (&dst)[12], const uint4* wb) {
#pragma unroll
  for (int i = 0; i < 12; ++i) dst[i] = wb[i * 64];
}

__device__ __forceinline__ void load_x(float4 (&dst)[2][2], const float* p0,
                                       const float* p1) {
  dst[0][0] = *(const float4*)(p0);
  dst[0][1] = *(const float4*)(p0 + 4);
  dst[1][0] = *(const float4*)(p1);
  dst[1][1] = *(const float4*)(p1 + 4);
}

__device__ __forceinline__ void mfma_step(const float4 (&xcur)[2][2],
                                          const uint4 (&wf)[12],
                                          f32x4 (&acc)[2][4]) {
  bf16x8 ah[2], am[2], al[2];
#pragma unroll
  for (int t = 0; t < 2; ++t) {
    const float4 v0 = xcur[t][0], v1 = xcur[t][1];
    const float e[8] = {v0.x, v0.y, v0.z, v0.w, v1.x, v1.y, v1.z, v1.w};
    FragU uh, um, ul;
    split3(e, uh.u, um.u, ul.u);
    ah[t] = uh.s;
    am[t] = um.s;
    al[t] = ul.s;
  }
#pragma unroll
  for (int nt = 0; nt < 4; ++nt) {
    FragU bh, bm, bl;
    bh.q = wf[nt * 3 + 0];
    bm.q = wf[nt * 3 + 1];
    bl.q = wf[nt * 3 + 2];
#pragma unroll
    for (int t = 0; t < 2; ++t) {
      f32x4 c = acc[t][nt];
      c = __builtin_amdgcn_mfma_f32_16x16x32_bf16(ah[t], bh.s, c, 0, 0, 0);
      c = __builtin_amdgcn_mfma_f32_16x16x32_bf16(am[t], bh.s, c, 0, 0, 0);
      c = __builtin_amdgcn_mfma_f32_16x16x32_bf16(ah[t], bm.s, c, 0, 0, 0);
      c = __builtin_amdgcn_mfma_f32_16x16x32_bf16(al[t], bh.s, c, 0, 0, 0);
      c = __builtin_amdgcn_mfma_f32_16x16x32_bf16(ah[t], bl.s, c, 0, 0, 0);
      c = __builtin_amdgcn_mfma_f32_16x16x32_bf16(am[t], bm.s, c, 0, 0, 0);
      acc[t][nt] = c;
    }
  }
}

// ---- main kernel ----
__global__ __launch_bounds__(512, 1) void moe_gate_kernel(
    const float* __restrict__ x, const uint4* __restrict__ wf_g,
    float* __restrict__ out, int n_tokens) {
  __shared__ float part[8 * 2048];      // 64 KB: per-wave C fragments
  __shared__ float logits[N_EXP * 64];  // 16 KB

  const int tid = threadIdx.x;
  const int l = tid & 63;
  const int w = tid >> 6;
  const int tp = w & 1;   // token half (32 tokens)
  const int kq = w >> 1;  // k quarter (512 k)
  const int t0 = blockIdx.x * TOK;

  // x A-frag addresses: tile t in {0,1}: row = t0+tp*32+t*16+(l&15),
  // col = kq*512 + s*32 + (l>>4)*8 + h*4
  const float* xp0 =
      x + (size_t)(t0 + tp * 32 + (l & 15)) * H_DIM + kq * 512 + ((l >> 4) << 3);
  const float* xp1 = xp0 + (size_t)16 * H_DIM;

  const uint4* wbase = wf_g + (size_t)(kq * 16) * 768 + l;

  f32x4 acc[2][4];
#pragma unroll
  for (int t = 0; t < 2; ++t)
#pragma unroll
    for (int nt = 0; nt < 4; ++nt) acc[t][nt] = (f32x4){0.f, 0.f, 0.f, 0.f};

  uint4 wfA[12], wfB[12];
  float4 xA[2][2], xB[2][2], xC[2][2];

  // prologue: B(0) first (L2-fast), then x(0), x(1)
  load_b(wfA, wbase);
  load_x(xA, xp0, xp1);
  load_x(xB, xp0 + 32, xp1 + 32);

#pragma unroll 2
  for (int s = 0; s < NSTEP - 2; ++s) {
    // issue order matters (vmcnt retires in order): L2-fast B(s+1) FIRST,
    // HBM-slow x(s+2) LAST. MFMA below consumes wfA (issued a full step
    // ago) -> compiler waits vmcnt(16), no load latency on critical path.
    load_b(wfB, wbase + (size_t)(s + 1) * 768);
    load_x(xC, xp0 + (s + 2) * 32, xp1 + (s + 2) * 32);
    mfma_step(xA, wfA, acc);
    // rotate (static indices; copy-prop under unroll-2)
#pragma unroll
    for (int i = 0; i < 12; ++i) wfA[i] = wfB[i];
#pragma unroll
    for (int t = 0; t < 2; ++t)
#pragma unroll
      for (int h = 0; h < 2; ++h) {
        xA[t][h] = xB[t][h];
        xB[t][h] = xC[t][h];
      }
  }
  // step NSTEP-2: prefetch B only
  load_b(wfB, wbase + (size_t)(NSTEP - 1) * 768);
  mfma_step(xA, wfA, acc);
#pragma unroll
  for (int i = 0; i < 12; ++i) wfA[i] = wfB[i];
#pragma unroll
  for (int t = 0; t < 2; ++t)
#pragma unroll
    for (int h = 0; h < 2; ++h) xA[t][h] = xB[t][h];
  // step NSTEP-1: no prefetch
  mfma_step(xA, wfA, acc);

  // ---- store per-wave C fragments (2048 floats/wave); reduce; top-8 ----
#pragma unroll
  for (int t = 0; t < 2; ++t)
#pragma unroll
    for (int nt = 0; nt < 4; ++nt)
      *(float4*)&part[w * 2048 + (t * 4 + nt) * 256 + l * 4] =
          make_float4(acc[t][nt][0], acc[t][nt][1], acc[t][nt][2],
                      acc[t][nt][3]);
  __syncthreads();

  for (int z = tid; z < N_EXP * 64; z += 512) {
    const int e = z >> 6, t64 = z & 63;
    const int tpz = t64 >> 5, tz = (t64 >> 4) & 1;
    const int qz = (t64 >> 2) & 3, rz = t64 & 3;
    const int lz = qz * 16 + (e & 15);
    const int ntz = e >> 4;
    const int idx = (tz * 4 + ntz) * 256 + lz * 4 + rz;
    float v = ((part[(0 * 2 + tpz) * 2048 + idx] +
                part[(1 * 2 + tpz) * 2048 + idx]) +
               (part[(2 * 2 + tpz) * 2048 + idx] +
                part[(3 * 2 + tpz) * 2048 + idx]));
    logits[z] = v;  // z = e*64 + t64
  }
  __syncthreads();

  if (w != 0) return;

  // ---- wave 0: per-lane top-8 over 64 logits (lane = token) ----
  float lg[N_EXP];
#pragma unroll
  for (int e = 0; e < N_EXP; ++e) lg[e] = logits[e * 64 + l];

  float bw[TOPK];
  int bi[TOPK];
#pragma unroll
  for (int k = 0; k < TOPK; ++k) {
    float m = lg[0];
    int mi = 0;
#pragma unroll
    for (int e = 1; e < N_EXP; ++e) {
      if (lg[e] > m) {  // strict > keeps lowest index on tie (lax.top_k)
        m = lg[e];
        mi = e;
      }
    }
    bw[k] = m;
    bi[k] = mi;
#pragma unroll
    for (int e = 0; e < N_EXP; ++e)
      if (e == mi) lg[e] = -INFINITY;
  }

  // softmax over top-8 == full softmax renormalized to top-8 (exact)
  const float mx = bw[0];
  float ew[TOPK];
  float s = 0.f;
#pragma unroll
  for (int k = 0; k < TOPK; ++k) {
    ew[k] = expf(bw[k] - mx);
    s += ew[k];
  }
  const float inv = 1.f / s;

  float4 w0, w1, i0, i1;
  w0.x = ew[0] * inv; w0.y = ew[1] * inv; w0.z = ew[2] * inv; w0.w = ew[3] * inv;
  w1.x = ew[4] * inv; w1.y = ew[5] * inv; w1.z = ew[6] * inv; w1.w = ew[7] * inv;
  i0.x = (float)bi[0]; i0.y = (float)bi[1]; i0.z = (float)bi[2]; i0.w = (float)bi[3];
  i1.x = (float)bi[4]; i1.y = (float)bi[5]; i1.z = (float)bi[6]; i1.w = (float)bi[7];

  const int t = t0 + l;
  float4* ow = reinterpret_cast<float4*>(out + (size_t)t * TOPK);
  ow[0] = w0;
  ow[1] = w1;
  float4* oi =
      reinterpret_cast<float4*>(out + (size_t)n_tokens * TOPK + (size_t)t * TOPK);
  oi[0] = i0;
  oi[1] = i1;
}

extern "C" void kernel_launch(void* const* d_in, const int* in_sizes, int n_in,
                              void* d_out, int out_size, void* d_ws,
                              size_t ws_size, hipStream_t stream) {
  const float* x = (const float*)d_in[0];
  const float* w = (const float*)d_in[1];
  float* out = (float*)d_out;
  const int n_tokens = in_sizes[0] / H_DIM;  // 16384
  // prologue: split W into B-fragment-ordered bf16x3 (768 KB in d_ws)
  w_split_kernel<<<64, 256, 0, stream>>>(w, (uint4*)d_ws);
  const int n_blocks = n_tokens / TOK;  // 256
  moe_gate_kernel<<<n_blocks, 512, 0, stream>>>(x, (const uint4*)d_ws, out,
                                                n_tokens);
}